// Round 15
// baseline (46.402 us; speedup 1.0000x reference)
//
#include <hip/hip_runtime.h>
#include <math.h>

#define BATCH 64
#define DK 256
#define FEATURES 512
#define NUM_TAPE 2048
#define TOPK 512
#define TOP16 16
#define THRESH 4.0f
#define KCHUNKS 8
#define KPER (TOPK / KCHUNKS) /* 64 */
#define CAP 640

// output layout (floats)
#define OFF_Q 0
#define OFF_HP (BATCH * DK)                    /* 16384 */
#define OFF_REM (OFF_HP + BATCH)               /* 16448 */
#define OFF_NUP (OFF_REM + BATCH)              /* 16512 */
#define OFF_MASK (OFF_NUP + BATCH)             /* 16576 */
#define OFF_TSEL (OFF_MASK + BATCH * NUM_TAPE) /* 147648 */

// ws layout (floats)
#define WS_SCORES 0    /* 64*2048 */
#define WS_PART 131072 /* 64*8*512 */

__device__ __forceinline__ unsigned f2key(float f) {
    unsigned u = __float_as_uint(f);
    return (u & 0x80000000u) ? ~u : (u | 0x80000000u);
}

// descending-order bucket find: sh_digit = d with suffix(d) >= KREM > suffix(d+1),
// sh_hi = suffix(d+1). hist[256] valid on entry; hist is ZEROED for the next pass
// (each thread zeroes its bin right after reading it).
#define RADIX_FIND(KREM)                                              \
    {                                                                 \
        int v = 0, hcnt = 0;                                          \
        if (tid < 256) {                                              \
            hcnt = hist[tid];                                         \
            hist[tid] = 0;                                            \
            v = hcnt;                                                 \
            _Pragma("unroll") for (int off = 1; off < 64; off <<= 1) {\
                const int t = __shfl_down(v, off);                    \
                if (lane + off < 64) v += t;                          \
            }                                                         \
            if (lane == 0) chunkTot[wv] = v;                          \
        }                                                             \
        __syncthreads();                                              \
        if (tid < 256) {                                              \
            _Pragma("unroll") for (int w2 = 0; w2 < 4; ++w2)          \
                if (w2 > wv) v += chunkTot[w2];                       \
            if (v >= (KREM) && (v - hcnt) < (KREM)) {                 \
                sh_digit = tid;                                       \
                sh_hi = v - hcnt;                                     \
            }                                                         \
        }                                                             \
        __syncthreads();                                              \
    }

// ---------------- Kernel A: scores[b][n] = dot(q[b,:256], tape[b,n,:256]) ----------
// 8 lanes per token; 3-step shfl reduce (one shfl serves 8 tokens at once).
__global__ __launch_bounds__(256) void k_scores(const float* __restrict__ q,
                                                const float* __restrict__ tape,
                                                float* __restrict__ scores) {
    const int b = blockIdx.y;
    const int tid = threadIdx.x;
    const int sub = tid & 7;                       // lane within token-group
    const int tok = blockIdx.x * 32 + (tid >> 3);  // 32 tokens per block
    const float4* qp = reinterpret_cast<const float4*>(q + (size_t)b * DK);
    const float4* tp =
        reinterpret_cast<const float4*>(tape + ((size_t)b * NUM_TAPE + tok) * FEATURES);
    float s = 0.f;
#pragma unroll
    for (int j = 0; j < 8; ++j) {
        const float4 qf = qp[sub + 8 * j];
        const float4 tf = tp[sub + 8 * j];
        s += qf.x * tf.x + qf.y * tf.y + qf.z * tf.z + qf.w * tf.w;
    }
    s += __shfl_xor(s, 1);
    s += __shfl_xor(s, 2);
    s += __shfl_xor(s, 4);
    if (sub == 0) scores[b * NUM_TAPE + tok] = s;
}

// ======== Kernel B: redundant contention-free select + chunked gather ==============
// Block (kc, b) re-runs the identical deterministic top-512 selection for batch b,
// keeps positions [kc*64, (kc+1)*64) of the index-ordered compacted list, and
// gathers those 64 full 2KB rows (8 rows in flight) -> partials[b][kc].
// kc==0 additionally writes scalars + score_mask. 512 blocks = 2/CU: co-resident
// blocks overlap select (barrier-bound) with gather (memory-bound).
__global__ __launch_bounds__(512) void k_select_gather(
    const float* __restrict__ scores, const float* __restrict__ mask_in,
    const float* __restrict__ hp_in, const float* __restrict__ rem_in,
    const float* __restrict__ nup_in, const float* __restrict__ tape,
    float* __restrict__ partials, float* __restrict__ out) {
    const int b = blockIdx.y;
    const int kc = blockIdx.x;
    const int tid = threadIdx.x;
    const int lane = tid & 63;
    const int wv = tid >> 6;

    __shared__ int hist[256];
    __shared__ int chunkTot[4];
    __shared__ int sh_digit, sh_hi;
    __shared__ unsigned ckey[CAP];
    __shared__ int cidx[CAP];
    __shared__ int csel[CAP];
    __shared__ int cand_n;
    __shared__ float redf[3][8];
    __shared__ int wtot[8];
    __shared__ float gl_w[KPER];
    __shared__ int gl_idx[KPER];
    __shared__ float4 shacc[1024];

    // 4 elements/thread, e = 4*tid + j
    const float4 sc = reinterpret_cast<const float4*>(scores + (size_t)b * NUM_TAPE)[tid];
    const float4 mk = reinterpret_cast<const float4*>(mask_in + (size_t)b * NUM_TAPE)[tid];
    const float4 s0 = reinterpret_cast<const float4*>(scores)[tid]; // row 0 (flatten bug)
    unsigned key[4];
    key[0] = f2key(sc.x - mk.x * 1e9f);
    key[1] = f2key(sc.y - mk.y * 1e9f);
    key[2] = f2key(sc.z - mk.z * 1e9f);
    key[3] = f2key(sc.w - mk.w * 1e9f);
    const float s0v[4] = {s0.x * 0.0625f, s0.y * 0.0625f, s0.z * 0.0625f, s0.w * 0.0625f};

    // ---- select-1 (top-512): pass A on byte3
    if (tid < 256) hist[tid] = 0;
    __syncthreads();
#pragma unroll
    for (int j = 0; j < 4; ++j) atomicAdd(&hist[key[j] >> 24], 1);
    __syncthreads();
    RADIX_FIND(TOPK);
    const unsigned B1 = (unsigned)sh_digit;
    const int aboveA = sh_hi;
    // hist already zeroed inside RADIX_FIND
#pragma unroll
    for (int j = 0; j < 4; ++j)
        if ((key[j] >> 24) == B1) atomicAdd(&hist[(key[j] >> 16) & 0xFF], 1);
    if (tid == 511) cand_n = 0;  // folded reset (published by next barrier)
    __syncthreads();
    RADIX_FIND(TOPK - aboveA);
    const unsigned P16 = (B1 << 8) | (unsigned)sh_digit;
    const int krem512 = (TOPK - aboveA) - sh_hi;

    // candidates (16-bit prefix == P16, few): exact rank by (key desc, idx asc)
    int cpos[4];
#pragma unroll
    for (int j = 0; j < 4; ++j) {
        cpos[j] = -1;
        if ((key[j] >> 16) == P16) {
            const int p = atomicAdd(&cand_n, 1);
            if (p < CAP) {
                ckey[p] = key[j];
                cidx[p] = 4 * tid + j;
            }
            cpos[j] = p;
        }
    }
    __syncthreads();
    int cn = cand_n < CAP ? cand_n : CAP;
    for (int t = tid; t < cn; t += 512) {
        const unsigned k = ckey[t];
        const int i = cidx[t];
        int r = 0;
        for (int u = 0; u < cn; ++u) {
            const unsigned ko = ckey[u];
            r += (ko > k) || (ko == k && cidx[u] < i);
        }
        csel[t] = (r < krem512);
    }
    __syncthreads();
    bool sel[4];
#pragma unroll
    for (int j = 0; j < 4; ++j)
        sel[j] = ((key[j] >> 16) > P16) ||
                 (cpos[j] >= 0 && cpos[j] < CAP && csel[cpos[j]]);
    __syncthreads();

    // ---- select-2 (top-16 among selected): pass C on byte3 (hist zeroed above)
#pragma unroll
    for (int j = 0; j < 4; ++j)
        if (sel[j]) atomicAdd(&hist[key[j] >> 24], 1);
    __syncthreads();
    RADIX_FIND(TOP16);
    const unsigned C1 = (unsigned)sh_digit;
    const int aboveC = sh_hi;
    // pass D on byte2 among selected keys with byte3 == C1
#pragma unroll
    for (int j = 0; j < 4; ++j)
        if (sel[j] && (key[j] >> 24) == C1) atomicAdd(&hist[(key[j] >> 16) & 0xFF], 1);
    if (tid == 511) cand_n = 0;  // folded reset
    __syncthreads();
    RADIX_FIND(TOP16 - aboveC);
    const unsigned P16_2 = (C1 << 8) | (unsigned)sh_digit;
    const int krem16 = (TOP16 - aboveC) - sh_hi;

    // candidates (selected, 16-bit prefix == P16_2, few): exact rank
    int c2pos[4];
#pragma unroll
    for (int j = 0; j < 4; ++j) {
        c2pos[j] = -1;
        if (sel[j] && (key[j] >> 16) == P16_2) {
            const int p = atomicAdd(&cand_n, 1);
            if (p < CAP) {
                ckey[p] = key[j];
                cidx[p] = 4 * tid + j;
            }
            c2pos[j] = p;
        }
    }
    __syncthreads();
    cn = cand_n < CAP ? cand_n : CAP;
    for (int t = tid; t < cn; t += 512) {
        const unsigned k = ckey[t];
        const int i = cidx[t];
        int r = 0;
        for (int u = 0; u < cn; ++u) {
            const unsigned ko = ckey[u];
            r += (ko > k) || (ko == k && cidx[u] < i);
        }
        csel[t] = (r < krem16);
    }
    __syncthreads();
    bool in16[4];
#pragma unroll
    for (int j = 0; j < 4; ++j)
        in16[j] = sel[j] && (((key[j] >> 16) > P16_2) ||
                             (c2pos[j] >= 0 && c2pos[j] < CAP && csel[c2pos[j]]));

    // ---- no-max softmax over row-0 scores (bounded inputs; one 3-value reduction)
    float ev[4];
    float se = 0.f, se2 = 0.f, s16l = 0.f;
#pragma unroll
    for (int j = 0; j < 4; ++j) {
        ev[j] = sel[j] ? expf(s0v[j]) : 0.f;
        se += ev[j];
        se2 += ev[j] * ev[j];
        if (in16[j]) s16l += ev[j];
    }
#pragma unroll
    for (int off = 32; off; off >>= 1) {
        se += __shfl_xor(se, off);
        se2 += __shfl_xor(se2, off);
        s16l += __shfl_xor(s16l, off);
    }
    if (lane == 0) {
        redf[0][wv] = se;
        redf[1][wv] = se2;
        redf[2][wv] = s16l;
    }
    __syncthreads();
    float S = 0.f, S2 = 0.f, S16 = 0.f;
#pragma unroll
    for (int w2 = 0; w2 < 8; ++w2) {
        S += redf[0][w2];
        S2 += redf[1][w2];
        S16 += redf[2][w2];
    }
    const float inv = 1.0f / S;
    const float sumsq = S2 * inv * inv;
    const float s16 = S16 * inv;

    float w[4];
#pragma unroll
    for (int j = 0; j < 4; ++j) w[j] = ev[j] * inv;

    // ---- deterministic compaction; keep entries with global position in
    // [kc*KPER, (kc+1)*KPER) in LDS (ascending element index order)
    {
        const int cnt = (sel[0] ? 1 : 0) + (sel[1] ? 1 : 0) + (sel[2] ? 1 : 0) + (sel[3] ? 1 : 0);
        int pre = cnt;
#pragma unroll
        for (int off = 1; off < 64; off <<= 1) {
            const int t = __shfl_up(pre, off);
            if (lane >= off) pre += t;
        }
        if (lane == 63) wtot[wv] = pre;
        __syncthreads();
        int base = 0;
        for (int w2 = 0; w2 < wv; ++w2) base += wtot[w2];
        int p = base + pre - cnt;
        const int lo = kc * KPER, hi = lo + KPER;
#pragma unroll
        for (int j = 0; j < 4; ++j) {
            if (sel[j]) {
                if (p >= lo && p < hi) {
                    gl_idx[p - lo] = 4 * tid + j;
                    gl_w[p - lo] = w[j];
                }
                ++p;
            }
        }
    }

    // ---- kc==0 writes scalars + mask (flags thread-local, no scatter)
    if (kc == 0) {
        if (tid == 0) {
            const float hp = hp_in[b], rem = rem_in[b], nup = nup_in[b];
            const float entropy = 1.0f - sumsq;
            const float still = (hp < THRESH) ? 1.f : 0.f;
            const float nh = ((hp + s16) >= THRESH ? 1.f : 0.f) * still;
            const float st2 = still - nh;
            out[OFF_REM + b] = rem + (nh + st2) * entropy;
            float hp1 = hp + s16 * st2;
            hp1 = hp1 + nh * (THRESH - hp1);
            out[OFF_HP + b] = hp1;
            out[OFF_NUP + b] = nup + st2 + nh;
        }
        float4 om;
        om.x = mk.x + (sel[0] ? 1.f : 0.f);
        om.y = mk.y + (sel[1] ? 1.f : 0.f);
        om.z = mk.z + (sel[2] ? 1.f : 0.f);
        om.w = mk.w + (sel[3] ? 1.f : 0.f);
        reinterpret_cast<float4*>(out + OFF_MASK + (size_t)b * NUM_TAPE)[tid] = om;
    }
    __syncthreads();

    // ---- gather this chunk's 64 rows (full 2KB rows), 8 rows in flight:
    // 8 row-groups x 64 lanes, each lane reads 2 float4 (f4 = fl and fl+64)
    const int rg = tid >> 6;  // 0..7 row-group
    const int fl = tid & 63;  // 0..63
    float4 acc0 = {0.f, 0.f, 0.f, 0.f};
    float4 acc1 = {0.f, 0.f, 0.f, 0.f};
#pragma unroll 2
    for (int k = rg; k < KPER; k += 8) {
        const float ww = gl_w[k];
        const float4* rp =
            reinterpret_cast<const float4*>(tape + ((size_t)b * NUM_TAPE + gl_idx[k]) * FEATURES);
        const float4 t0 = rp[fl];
        const float4 t1 = rp[64 + fl];
        acc0.x = fmaf(ww, t0.x, acc0.x);
        acc0.y = fmaf(ww, t0.y, acc0.y);
        acc0.z = fmaf(ww, t0.z, acc0.z);
        acc0.w = fmaf(ww, t0.w, acc0.w);
        acc1.x = fmaf(ww, t1.x, acc1.x);
        acc1.y = fmaf(ww, t1.y, acc1.y);
        acc1.z = fmaf(ww, t1.z, acc1.z);
        acc1.w = fmaf(ww, t1.w, acc1.w);
    }
    shacc[rg * 128 + fl] = acc0;
    shacc[rg * 128 + 64 + fl] = acc1;
    __syncthreads();
    if (tid < 128) {
        float4 s = {0.f, 0.f, 0.f, 0.f};
#pragma unroll
        for (int r = 0; r < 8; ++r) {
            const float4 a = shacc[r * 128 + tid];
            s.x += a.x;
            s.y += a.y;
            s.z += a.z;
            s.w += a.w;
        }
        reinterpret_cast<float4*>(partials + ((size_t)b * KCHUNKS + kc) * FEATURES)[tid] = s;
    }
}

// -------- Kernel C: reduce 8 partials -> token_sel + query update (no LDS) ---------
__global__ __launch_bounds__(128) void k_finish(const float* __restrict__ q,
                                                const float* __restrict__ partials,
                                                float* __restrict__ out) {
    const int b = blockIdx.x;
    const int f4 = threadIdx.x;  // 0..127
    const float4* pp = reinterpret_cast<const float4*>(partials + (size_t)b * KCHUNKS * FEATURES);
    float4 s = {0.f, 0.f, 0.f, 0.f};
#pragma unroll
    for (int r = 0; r < KCHUNKS; ++r) {
        const float4 a = pp[r * 128 + f4];
        s.x += a.x;
        s.y += a.y;
        s.z += a.z;
        s.w += a.w;
    }
    reinterpret_cast<float4*>(out + OFF_TSEL + (size_t)b * FEATURES)[f4] = s;
    if (f4 < 64) {
        const float4 qv = reinterpret_cast<const float4*>(q + (size_t)b * DK)[f4];
        float4 nq;
        nq.x = (qv.x + s.x) * 0.5f;
        nq.y = (qv.y + s.y) * 0.5f;
        nq.z = (qv.z + s.z) * 0.5f;
        nq.w = (qv.w + s.w) * 0.5f;
        reinterpret_cast<float4*>(out + OFF_Q + (size_t)b * DK)[f4] = nq;
    }
}

extern "C" void kernel_launch(void* const* d_in, const int* in_sizes, int n_in,
                              void* d_out, int out_size, void* d_ws, size_t ws_size,
                              hipStream_t stream) {
    const float* q = (const float*)d_in[0];
    const float* hp = (const float*)d_in[1];
    const float* rem = (const float*)d_in[2];
    const float* nup = (const float*)d_in[3];
    const float* mask = (const float*)d_in[4];
    const float* tape = (const float*)d_in[5];
    float* out = (float*)d_out;
    float* ws = (float*)d_ws;

    float* scores = ws + WS_SCORES;
    float* partials = ws + WS_PART;

    k_scores<<<dim3(NUM_TAPE / 32, BATCH), 256, 0, stream>>>(q, tape, scores);
    k_select_gather<<<dim3(KCHUNKS, BATCH), 512, 0, stream>>>(
        scores, mask, hp, rem, nup, tape, partials, out);
    k_finish<<<BATCH, 128, 0, stream>>>(q, partials, out);
}

// Round 16
// 45.144 us; speedup vs baseline: 1.0279x; 1.0279x over previous
//
#include <hip/hip_runtime.h>
#include <math.h>

#define BATCH 64
#define DK 256
#define FEATURES 512
#define NUM_TAPE 2048
#define TOPK 512
#define TOP16 16
#define THRESH 4.0f
#define KCHUNKS 4
#define KPER (TOPK / KCHUNKS) /* 128 */
#define CAP 640

// output layout (floats)
#define OFF_Q 0
#define OFF_HP (BATCH * DK)                    /* 16384 */
#define OFF_REM (OFF_HP + BATCH)               /* 16448 */
#define OFF_NUP (OFF_REM + BATCH)              /* 16512 */
#define OFF_MASK (OFF_NUP + BATCH)             /* 16576 */
#define OFF_TSEL (OFF_MASK + BATCH * NUM_TAPE) /* 147648 */

// ws layout (floats)
#define WS_SCORES 0    /* 64*2048 */
#define WS_PART 131072 /* 64*4*512 */

__device__ __forceinline__ unsigned f2key(float f) {
    unsigned u = __float_as_uint(f);
    return (u & 0x80000000u) ? ~u : (u | 0x80000000u);
}

// descending-order bucket find: sh_digit = d with suffix(d) >= KREM > suffix(d+1),
// sh_hi = suffix(d+1). hist[256] valid on entry; hist is ZEROED for the next pass
// (each thread zeroes its bin right after reading it).
#define RADIX_FIND(KREM)                                              \
    {                                                                 \
        int v = 0, hcnt = 0;                                          \
        if (tid < 256) {                                              \
            hcnt = hist[tid];                                         \
            hist[tid] = 0;                                            \
            v = hcnt;                                                 \
            _Pragma("unroll") for (int off = 1; off < 64; off <<= 1) {\
                const int t = __shfl_down(v, off);                    \
                if (lane + off < 64) v += t;                          \
            }                                                         \
            if (lane == 0) chunkTot[wv] = v;                          \
        }                                                             \
        __syncthreads();                                              \
        if (tid < 256) {                                              \
            _Pragma("unroll") for (int w2 = 0; w2 < 4; ++w2)          \
                if (w2 > wv) v += chunkTot[w2];                       \
            if (v >= (KREM) && (v - hcnt) < (KREM)) {                 \
                sh_digit = tid;                                       \
                sh_hi = v - hcnt;                                     \
            }                                                         \
        }                                                             \
        __syncthreads();                                              \
    }

// ---------------- Kernel A: scores[b][n] = dot(q[b,:256], tape[b,n,:256]) ----------
// 8 lanes per token: each thread reads 8 stride-8 float4s (8 independent loads,
// 128B-coalesced per 8-lane group), then a 3-step shfl reduce. One shfl
// instruction serves 8 tokens at once.
__global__ __launch_bounds__(256) void k_scores(const float* __restrict__ q,
                                                const float* __restrict__ tape,
                                                float* __restrict__ scores) {
    const int b = blockIdx.y;
    const int tid = threadIdx.x;
    const int sub = tid & 7;                       // lane within token-group
    const int tok = blockIdx.x * 32 + (tid >> 3);  // 32 tokens per block
    const float4* qp = reinterpret_cast<const float4*>(q + (size_t)b * DK);
    const float4* tp =
        reinterpret_cast<const float4*>(tape + ((size_t)b * NUM_TAPE + tok) * FEATURES);
    float s = 0.f;
#pragma unroll
    for (int j = 0; j < 8; ++j) {
        const float4 qf = qp[sub + 8 * j];
        const float4 tf = tp[sub + 8 * j];
        s += qf.x * tf.x + qf.y * tf.y + qf.z * tf.z + qf.w * tf.w;
    }
    s += __shfl_xor(s, 1);
    s += __shfl_xor(s, 2);
    s += __shfl_xor(s, 4);
    if (sub == 0) scores[b * NUM_TAPE + tok] = s;
}

// ======== Kernel B: redundant contention-free select + chunked gather ==============
// Block (kc, b) re-runs the identical deterministic top-512 selection for batch b
// (no cross-block sync: identical inputs + identical code => identical results),
// keeps the chunk of the index-ordered compacted list with global positions in
// [kc*128, (kc+1)*128), and gathers those 128 full 2KB rows -> partials[b][kc].
// kc==0 additionally writes scalars + score_mask.
__global__ __launch_bounds__(512) void k_select_gather(
    const float* __restrict__ scores, const float* __restrict__ mask_in,
    const float* __restrict__ hp_in, const float* __restrict__ rem_in,
    const float* __restrict__ nup_in, const float* __restrict__ tape,
    float* __restrict__ partials, float* __restrict__ out) {
    const int b = blockIdx.y;
    const int kc = blockIdx.x;
    const int tid = threadIdx.x;
    const int lane = tid & 63;
    const int wv = tid >> 6;

    __shared__ int hist[256];
    __shared__ int chunkTot[4];
    __shared__ int sh_digit, sh_hi;
    __shared__ unsigned ckey[CAP];
    __shared__ int cidx[CAP];
    __shared__ int csel[CAP];
    __shared__ int cand_n;
    __shared__ float redf[3][8];
    __shared__ int wtot[8];
    __shared__ float gl_w[KPER];
    __shared__ int gl_idx[KPER];
    __shared__ float4 shacc[512];

    // 4 elements/thread, e = 4*tid + j
    const float4 sc = reinterpret_cast<const float4*>(scores + (size_t)b * NUM_TAPE)[tid];
    const float4 mk = reinterpret_cast<const float4*>(mask_in + (size_t)b * NUM_TAPE)[tid];
    const float4 s0 = reinterpret_cast<const float4*>(scores)[tid]; // row 0 (flatten bug)
    unsigned key[4];
    key[0] = f2key(sc.x - mk.x * 1e9f);
    key[1] = f2key(sc.y - mk.y * 1e9f);
    key[2] = f2key(sc.z - mk.z * 1e9f);
    key[3] = f2key(sc.w - mk.w * 1e9f);
    const float s0v[4] = {s0.x * 0.0625f, s0.y * 0.0625f, s0.z * 0.0625f, s0.w * 0.0625f};

    // ---- select-1 (top-512): pass A on byte3
    if (tid < 256) hist[tid] = 0;
    __syncthreads();
#pragma unroll
    for (int j = 0; j < 4; ++j) atomicAdd(&hist[key[j] >> 24], 1);
    __syncthreads();
    RADIX_FIND(TOPK);
    const unsigned B1 = (unsigned)sh_digit;
    const int aboveA = sh_hi;
    // hist already zeroed inside RADIX_FIND
#pragma unroll
    for (int j = 0; j < 4; ++j)
        if ((key[j] >> 24) == B1) atomicAdd(&hist[(key[j] >> 16) & 0xFF], 1);
    __syncthreads();
    RADIX_FIND(TOPK - aboveA);
    const unsigned P16 = (B1 << 8) | (unsigned)sh_digit;
    const int krem512 = (TOPK - aboveA) - sh_hi;

    // candidates (16-bit prefix == P16, few): exact rank by (key desc, idx asc)
    if (tid == 0) cand_n = 0;
    __syncthreads();
    int cpos[4];
#pragma unroll
    for (int j = 0; j < 4; ++j) {
        cpos[j] = -1;
        if ((key[j] >> 16) == P16) {
            const int p = atomicAdd(&cand_n, 1);
            if (p < CAP) {
                ckey[p] = key[j];
                cidx[p] = 4 * tid + j;
            }
            cpos[j] = p;
        }
    }
    __syncthreads();
    int cn = cand_n < CAP ? cand_n : CAP;
    for (int t = tid; t < cn; t += 512) {
        const unsigned k = ckey[t];
        const int i = cidx[t];
        int r = 0;
        for (int u = 0; u < cn; ++u) {
            const unsigned ko = ckey[u];
            r += (ko > k) || (ko == k && cidx[u] < i);
        }
        csel[t] = (r < krem512);
    }
    __syncthreads();
    bool sel[4];
#pragma unroll
    for (int j = 0; j < 4; ++j)
        sel[j] = ((key[j] >> 16) > P16) ||
                 (cpos[j] >= 0 && cpos[j] < CAP && csel[cpos[j]]);
    __syncthreads();

    // ---- select-2 (top-16 among selected): pass C on byte3 (hist zeroed above)
#pragma unroll
    for (int j = 0; j < 4; ++j)
        if (sel[j]) atomicAdd(&hist[key[j] >> 24], 1);
    __syncthreads();
    RADIX_FIND(TOP16);
    const unsigned C1 = (unsigned)sh_digit;
    const int aboveC = sh_hi;
    // pass D on byte2 among selected keys with byte3 == C1
#pragma unroll
    for (int j = 0; j < 4; ++j)
        if (sel[j] && (key[j] >> 24) == C1) atomicAdd(&hist[(key[j] >> 16) & 0xFF], 1);
    __syncthreads();
    RADIX_FIND(TOP16 - aboveC);
    const unsigned P16_2 = (C1 << 8) | (unsigned)sh_digit;
    const int krem16 = (TOP16 - aboveC) - sh_hi;

    // candidates (selected, 16-bit prefix == P16_2, few): exact rank
    if (tid == 0) cand_n = 0;
    __syncthreads();
    int c2pos[4];
#pragma unroll
    for (int j = 0; j < 4; ++j) {
        c2pos[j] = -1;
        if (sel[j] && (key[j] >> 16) == P16_2) {
            const int p = atomicAdd(&cand_n, 1);
            if (p < CAP) {
                ckey[p] = key[j];
                cidx[p] = 4 * tid + j;
            }
            c2pos[j] = p;
        }
    }
    __syncthreads();
    cn = cand_n < CAP ? cand_n : CAP;
    for (int t = tid; t < cn; t += 512) {
        const unsigned k = ckey[t];
        const int i = cidx[t];
        int r = 0;
        for (int u = 0; u < cn; ++u) {
            const unsigned ko = ckey[u];
            r += (ko > k) || (ko == k && cidx[u] < i);
        }
        csel[t] = (r < krem16);
    }
    __syncthreads();
    bool in16[4];
#pragma unroll
    for (int j = 0; j < 4; ++j)
        in16[j] = sel[j] && (((key[j] >> 16) > P16_2) ||
                             (c2pos[j] >= 0 && c2pos[j] < CAP && csel[c2pos[j]]));

    // ---- no-max softmax over row-0 scores (bounded inputs; one 3-value reduction)
    float ev[4];
    float se = 0.f, se2 = 0.f, s16l = 0.f;
#pragma unroll
    for (int j = 0; j < 4; ++j) {
        ev[j] = sel[j] ? expf(s0v[j]) : 0.f;
        se += ev[j];
        se2 += ev[j] * ev[j];
        if (in16[j]) s16l += ev[j];
    }
#pragma unroll
    for (int off = 32; off; off >>= 1) {
        se += __shfl_xor(se, off);
        se2 += __shfl_xor(se2, off);
        s16l += __shfl_xor(s16l, off);
    }
    if (lane == 0) {
        redf[0][wv] = se;
        redf[1][wv] = se2;
        redf[2][wv] = s16l;
    }
    __syncthreads();
    float S = 0.f, S2 = 0.f, S16 = 0.f;
#pragma unroll
    for (int w2 = 0; w2 < 8; ++w2) {
        S += redf[0][w2];
        S2 += redf[1][w2];
        S16 += redf[2][w2];
    }
    const float inv = 1.0f / S;
    const float sumsq = S2 * inv * inv;
    const float s16 = S16 * inv;

    float w[4];
#pragma unroll
    for (int j = 0; j < 4; ++j) w[j] = ev[j] * inv;

    // ---- deterministic compaction; keep entries with global position in
    // [kc*KPER, (kc+1)*KPER) in LDS (ascending element index order)
    {
        const int cnt = (sel[0] ? 1 : 0) + (sel[1] ? 1 : 0) + (sel[2] ? 1 : 0) + (sel[3] ? 1 : 0);
        int pre = cnt;
#pragma unroll
        for (int off = 1; off < 64; off <<= 1) {
            const int t = __shfl_up(pre, off);
            if (lane >= off) pre += t;
        }
        if (lane == 63) wtot[wv] = pre;
        __syncthreads();
        int base = 0;
        for (int w2 = 0; w2 < wv; ++w2) base += wtot[w2];
        int p = base + pre - cnt;
        const int lo = kc * KPER, hi = lo + KPER;
#pragma unroll
        for (int j = 0; j < 4; ++j) {
            if (sel[j]) {
                if (p >= lo && p < hi) {
                    gl_idx[p - lo] = 4 * tid + j;
                    gl_w[p - lo] = w[j];
                }
                ++p;
            }
        }
    }

    // ---- kc==0 writes scalars + mask (flags thread-local, no scatter)
    if (kc == 0) {
        if (tid == 0) {
            const float hp = hp_in[b], rem = rem_in[b], nup = nup_in[b];
            const float entropy = 1.0f - sumsq;
            const float still = (hp < THRESH) ? 1.f : 0.f;
            const float nh = ((hp + s16) >= THRESH ? 1.f : 0.f) * still;
            const float st2 = still - nh;
            out[OFF_REM + b] = rem + (nh + st2) * entropy;
            float hp1 = hp + s16 * st2;
            hp1 = hp1 + nh * (THRESH - hp1);
            out[OFF_HP + b] = hp1;
            out[OFF_NUP + b] = nup + st2 + nh;
        }
        float4 om;
        om.x = mk.x + (sel[0] ? 1.f : 0.f);
        om.y = mk.y + (sel[1] ? 1.f : 0.f);
        om.z = mk.z + (sel[2] ? 1.f : 0.f);
        om.w = mk.w + (sel[3] ? 1.f : 0.f);
        reinterpret_cast<float4*>(out + OFF_MASK + (size_t)b * NUM_TAPE)[tid] = om;
    }
    __syncthreads();

    // ---- gather this chunk's 128 rows (full 2KB rows), 4 row-groups x 128 f4
    const int rs = tid >> 7;   // 0..3
    const int f4 = tid & 127;  // float4 feature index
    float4 acc = {0.f, 0.f, 0.f, 0.f};
#pragma unroll 4
    for (int k = rs; k < KPER; k += 4) {
        const float ww = gl_w[k];
        const float4 t =
            reinterpret_cast<const float4*>(tape + ((size_t)b * NUM_TAPE + gl_idx[k]) * FEATURES)[f4];
        acc.x = fmaf(ww, t.x, acc.x);
        acc.y = fmaf(ww, t.y, acc.y);
        acc.z = fmaf(ww, t.z, acc.z);
        acc.w = fmaf(ww, t.w, acc.w);
    }
    shacc[tid] = acc;
    __syncthreads();
    if (tid < 128) {
        const float4 a0 = shacc[f4];
        const float4 a1 = shacc[128 + f4];
        const float4 a2 = shacc[256 + f4];
        const float4 a3 = shacc[384 + f4];
        float4 r;
        r.x = (a0.x + a1.x) + (a2.x + a3.x);
        r.y = (a0.y + a1.y) + (a2.y + a3.y);
        r.z = (a0.z + a1.z) + (a2.z + a3.z);
        r.w = (a0.w + a1.w) + (a2.w + a3.w);
        reinterpret_cast<float4*>(partials + ((size_t)b * KCHUNKS + kc) * FEATURES)[f4] = r;
    }
}

// -------- Kernel C: reduce 4 partials -> token_sel + query update (no LDS) ---------
__global__ __launch_bounds__(128) void k_finish(const float* __restrict__ q,
                                                const float* __restrict__ partials,
                                                float* __restrict__ out) {
    const int b = blockIdx.x;
    const int f4 = threadIdx.x;  // 0..127
    const float4* pp = reinterpret_cast<const float4*>(partials + (size_t)b * KCHUNKS * FEATURES);
    const float4 a0 = pp[0 * 128 + f4];
    const float4 a1 = pp[1 * 128 + f4];
    const float4 a2 = pp[2 * 128 + f4];
    const float4 a3 = pp[3 * 128 + f4];
    float4 s;
    s.x = (a0.x + a1.x) + (a2.x + a3.x);
    s.y = (a0.y + a1.y) + (a2.y + a3.y);
    s.z = (a0.z + a1.z) + (a2.z + a3.z);
    s.w = (a0.w + a1.w) + (a2.w + a3.w);
    reinterpret_cast<float4*>(out + OFF_TSEL + (size_t)b * FEATURES)[f4] = s;
    if (f4 < 64) {
        const float4 qv = reinterpret_cast<const float4*>(q + (size_t)b * DK)[f4];
        float4 nq;
        nq.x = (qv.x + s.x) * 0.5f;
        nq.y = (qv.y + s.y) * 0.5f;
        nq.z = (qv.z + s.z) * 0.5f;
        nq.w = (qv.w + s.w) * 0.5f;
        reinterpret_cast<float4*>(out + OFF_Q + (size_t)b * DK)[f4] = nq;
    }
}

extern "C" void kernel_launch(void* const* d_in, const int* in_sizes, int n_in,
                              void* d_out, int out_size, void* d_ws, size_t ws_size,
                              hipStream_t stream) {
    const float* q = (const float*)d_in[0];
    const float* hp = (const float*)d_in[1];
    const float* rem = (const float*)d_in[2];
    const float* nup = (const float*)d_in[3];
    const float* mask = (const float*)d_in[4];
    const float* tape = (const float*)d_in[5];
    float* out = (float*)d_out;
    float* ws = (float*)d_ws;

    float* scores = ws + WS_SCORES;
    float* partials = ws + WS_PART;

    k_scores<<<dim3(NUM_TAPE / 32, BATCH), 256, 0, stream>>>(q, tape, scores);
    k_select_gather<<<dim3(KCHUNKS, BATCH), 512, 0, stream>>>(
        scores, mask, hp, rem, nup, tape, partials, out);
    k_finish<<<BATCH, 128, 0, stream>>>(q, partials, out);
}